// Round 8
// baseline (155.391 us; speedup 1.0000x reference)
//
#include <hip/hip_runtime.h>
#include <hip/hip_bf16.h>
#include <math.h>

// Problem constants: B=256, V=2048, PD=1024, MD=512, H=512
typedef __attribute__((ext_vector_type(8))) short short8;
typedef __attribute__((ext_vector_type(4))) short short4v;
typedef __attribute__((ext_vector_type(4))) float float4v;
typedef __attribute__((ext_vector_type(2))) float float2v;

union f4u { float4v v4; float2v v2[2]; };

__device__ __forceinline__ int2 cvt2bf16x4(float4v v) {
    union { __hip_bfloat162 h2; int i; } u0, u1;
    u0.h2 = __float22bfloat162_rn(make_float2(v.x, v.y));  // v_cvt_pk_bf16_f32
    u1.h2 = __float22bfloat162_rn(make_float2(v.z, v.w));
    return make_int2(u0.i, u1.i);
}

// Fused dual GEMM + exp epilogue (plain [h][x] layout, contiguous stores).
//  z==0: EA[h][b] = exp(2*(patient@W1p^T + b1))   M=256,  K=1024
//  z==1: EM[h][v] = exp(2*(atc4@W1m^T))           M=2048, K=512
__global__ __launch_bounds__(256) void gemm_exp(
    const float* __restrict__ patient, const float* __restrict__ atc4,
    const float* __restrict__ W1, const float* __restrict__ b1,
    float* __restrict__ EA, float* __restrict__ EM)
{
    const float* A; const float* W; const float* bias; float* T;
    int lda, K, M;
    if (blockIdx.z == 0) {
        if (blockIdx.x >= 4) return;           // 4x8 tiles cover 256x512
        A = patient; lda = 1024; K = 1024; M = 256; bias = b1; T = EA; W = W1;
    } else {
        A = atc4;    lda = 512;  K = 512;  M = 2048; bias = nullptr; T = EM; W = W1 + 1024;
    }
    const int ldw = 1536;

    __shared__ short As[64][72];
    __shared__ short Bs[64][72];
    const int t = threadIdx.x;
    const int m0 = blockIdx.x * 64;
    const int n0 = blockIdx.y * 64;
    const int wave = t >> 6;
    const int lane = t & 63;
    const int wm = (wave & 1) * 32;
    const int wn = (wave >> 1) * 32;
    const int lrow = lane & 15;
    const int quad = lane >> 4;

    float4v acc[2][2];
    #pragma unroll
    for (int i = 0; i < 2; i++)
        #pragma unroll
        for (int j = 0; j < 2; j++)
            acc[i][j] = (float4v){0.f, 0.f, 0.f, 0.f};

    const int sr = t >> 2;        // staging row 0..63
    const int sc = (t & 3) * 16;  // staging col 0,16,32,48

    for (int k0 = 0; k0 < K; k0 += 64) {
        const float* ap = A + (size_t)(m0 + sr) * lda + (k0 + sc);
        const float* wp = W + (size_t)(n0 + sr) * ldw + (k0 + sc);
        #pragma unroll
        for (int ii = 0; ii < 4; ii++) {
            float4v av = *(const float4v*)(ap + ii * 4);
            float4v wv = *(const float4v*)(wp + ii * 4);
            *(int2*)&As[sr][sc + ii * 4] = cvt2bf16x4(av);
            *(int2*)&Bs[sr][sc + ii * 4] = cvt2bf16x4(wv);
        }
        __syncthreads();
        #pragma unroll
        for (int kk = 0; kk < 64; kk += 32) {
            short8 af[2], bfr[2];
            #pragma unroll
            for (int i = 0; i < 2; i++)
                af[i] = *(const short8*)&As[wm + i * 16 + lrow][kk + quad * 8];
            #pragma unroll
            for (int j = 0; j < 2; j++)
                bfr[j] = *(const short8*)&Bs[wn + j * 16 + lrow][kk + quad * 8];
            #pragma unroll
            for (int i = 0; i < 2; i++)
                #pragma unroll
                for (int j = 0; j < 2; j++)
                    acc[i][j] = __builtin_amdgcn_mfma_f32_16x16x32_bf16(
                        af[i], bfr[j], acc[i][j], 0, 0, 0);
        }
        __syncthreads();
    }

    // D layout (verified m89/m91): col(n)=lane&15, row(m)=quad*4+reg
    #pragma unroll
    for (int i = 0; i < 2; i++) {
        #pragma unroll
        for (int j = 0; j < 2; j++) {
            const int n  = n0 + wn + j * 16 + lrow;
            const int mb = m0 + wm + i * 16 + quad * 4;
            const float bn = bias ? bias[n] : 0.0f;
            float4v ev;
            #pragma unroll
            for (int r = 0; r < 4; r++)
                ev[r] = __expf(2.0f * (acc[i][j][r] + bn));
            *(float4v*)&T[(size_t)n * M + mb] = ev;
        }
    }
}

// partial[z][b][v] = sum_{h in 64-chunk z} [ w2[h] + c_h / d_h ],
//   c = -2*w2, d = 1 + Ea[h][b]*Em[h][v]    (w2*tanh(x) = w2 - 2*w2/(1+e^{2x}))
// 4-way h-pairing: one rcp per 4 h-terms,
//   sum_k c_k/d_k = (n01*e23 + n23*e01)/(e01*e23),  n01=c0*d1+c1*d0, e01=d0*d1.
//   All d >= 1: products bounded, no cancellation.
// Inner math on float2 halves -> v_pk_fma_f32/v_pk_mul_f32 (2-wide packed fp32);
// float4 LDS loads kept (halves are free register aliases).
// Tile: 64 v x 32 b x 64 h. Grid (32, 8, 8) = 2048 blocks (8/CU residency).
__global__ __launch_bounds__(256, 8) void pair_kernel(
    const float* __restrict__ EA, const float* __restrict__ EM,
    const float* __restrict__ w2, float* __restrict__ partial)
{
    __shared__ float sEA[32][36];   // [h][b], 32 cols used
    __shared__ float sEM[32][68];   // [h][v], 64 cols used
    __shared__ float4v sC4[16];     // -2*w2 quads for the 64-h chunk
    const int t  = threadIdx.x;
    const int v0 = blockIdx.x * 64;
    const int b0 = blockIdx.y * 32;
    const int h0 = blockIdx.z * 64;
    const int tx = t & 15;   // v = v0 + tx*4 + j
    const int ty = t >> 4;   // b = b0 + ty*2 + i

    if (t < 16) {
        float4v wv = *(const float4v*)(w2 + h0 + 4 * t);
        sC4[t] = -2.0f * wv;
    }

    f4u acc[2];
    acc[0].v4 = (float4v){0.f, 0.f, 0.f, 0.f};
    acc[1].v4 = (float4v){0.f, 0.f, 0.f, 0.f};
    const float2v one2 = {1.f, 1.f};

    const int rS = t >> 3;          // staging row 0..31
    const int cA = (t & 7) * 4;     // EA cols (32/row, 1 float4)
    const int cM = (t & 7) * 8;     // EM cols (64/row, 2 float4)

    float4v pA, pM0, pM1;
    // ---- load half 0 (h0 .. h0+31) ----
    {
        pA  = *(const float4v*)(EA + (size_t)(h0 + rS) * 256 + b0 + cA);
        const float* pm = EM + (size_t)(h0 + rS) * 2048 + v0 + cM;
        pM0 = *(const float4v*)pm;  pM1 = *(const float4v*)(pm + 4);
    }
    *(float4v*)&sEA[rS][cA] = pA;
    *(float4v*)&sEM[rS][cM] = pM0;  *(float4v*)&sEM[rS][cM + 4] = pM1;
    __syncthreads();
    // ---- prefetch half 1 into registers (in flight during compute 0) ----
    {
        pA  = *(const float4v*)(EA + (size_t)(h0 + 32 + rS) * 256 + b0 + cA);
        const float* pm = EM + (size_t)(h0 + 32 + rS) * 2048 + v0 + cM;
        pM0 = *(const float4v*)pm;  pM1 = *(const float4v*)(pm + 4);
    }

    #pragma unroll
    for (int half = 0; half < 2; half++) {
        #pragma unroll 2
        for (int q = 0; q < 8; q++) {           // 4 h per iteration
            const int hq = 4 * q;
            f4u em0, em1, em2, em3;
            em0.v4 = *(const float4v*)&sEM[hq    ][tx * 4];
            em1.v4 = *(const float4v*)&sEM[hq + 1][tx * 4];
            em2.v4 = *(const float4v*)&sEM[hq + 2][tx * 4];
            em3.v4 = *(const float4v*)&sEM[hq + 3][tx * 4];
            // both b's ea per h-row as one float2 (broadcast, conflict-free)
            const float2v ea0 = *(const float2v*)&sEA[hq    ][ty * 2];
            const float2v ea1 = *(const float2v*)&sEA[hq + 1][ty * 2];
            const float2v ea2 = *(const float2v*)&sEA[hq + 2][ty * 2];
            const float2v ea3 = *(const float2v*)&sEA[hq + 3][ty * 2];
            const float4v c = sC4[half * 8 + q];
            const float2v c0 = { c.x, c.x };
            const float2v c1 = { c.y, c.y };
            const float2v c2 = { c.z, c.z };
            const float2v c3 = { c.w, c.w };
            #pragma unroll
            for (int i = 0; i < 2; i++) {
                const float2v a0 = { ea0[i], ea0[i] };
                const float2v a1 = { ea1[i], ea1[i] };
                const float2v a2 = { ea2[i], ea2[i] };
                const float2v a3 = { ea3[i], ea3[i] };
                #pragma unroll
                for (int hv = 0; hv < 2; hv++) {   // low/high float2 of the v-quad
                    float2v d0 = __builtin_elementwise_fma(em0.v2[hv], a0, one2);
                    float2v d1 = __builtin_elementwise_fma(em1.v2[hv], a1, one2);
                    float2v d2 = __builtin_elementwise_fma(em2.v2[hv], a2, one2);
                    float2v d3 = __builtin_elementwise_fma(em3.v2[hv], a3, one2);
                    float2v e01 = d0 * d1;
                    float2v e23 = d2 * d3;
                    float2v n01 = __builtin_elementwise_fma(d1, c0, d0 * c1);
                    float2v n23 = __builtin_elementwise_fma(d3, c2, d2 * c3);
                    float2v num = __builtin_elementwise_fma(n01, e23, n23 * e01);
                    float2v den = e01 * e23;
                    float2v r = { __builtin_amdgcn_rcpf(den.x),
                                  __builtin_amdgcn_rcpf(den.y) };
                    acc[i].v2[hv] = __builtin_elementwise_fma(num, r, acc[i].v2[hv]);
                }
            }
        }
        if (half == 0) {
            __syncthreads();   // compute(0) done reading LDS
            *(float4v*)&sEA[rS][cA] = pA;
            *(float4v*)&sEM[rS][cM] = pM0;  *(float4v*)&sEM[rS][cM + 4] = pM1;
            __syncthreads();
        }
    }

    // chunk's sum(w2) from sC4 (sC4 = -2*w2)
    float4v w2q = sC4[0];
    for (int k = 1; k < 16; k++) w2q += sC4[k];
    const float w2s = -0.5f * (w2q.x + w2q.y + w2q.z + w2q.w);

    const size_t pb = (size_t)blockIdx.z * (256 * 2048);
    #pragma unroll
    for (int i = 0; i < 2; i++) {
        float4v o = acc[i].v4 + w2s;
        *(float4v*)&partial[pb + (size_t)(b0 + ty * 2 + i) * 2048 + v0 + tx * 4] = o;
    }
}

__global__ __launch_bounds__(256) void reduce_kernel(
    const float* __restrict__ partial, const float* __restrict__ b2,
    float* __restrict__ out)
{
    const int i = (blockIdx.x * 256 + threadIdx.x) * 4;
    const float bb = b2[0];
    float4v s = *(const float4v*)&partial[i];
    #pragma unroll
    for (int z = 1; z < 8; z++)
        s += *(const float4v*)&partial[(size_t)z * 524288 + i];
    float4v o = s + bb;
    *(float4v*)&out[i] = o;
}

extern "C" void kernel_launch(void* const* d_in, const int* in_sizes, int n_in,
                              void* d_out, int out_size, void* d_ws, size_t ws_size,
                              hipStream_t stream)
{
    const float* patient = (const float*)d_in[0]; // 256x1024
    const float* atc4    = (const float*)d_in[1]; // 2048x512
    const float* W1      = (const float*)d_in[2]; // 512x1536
    const float* b1      = (const float*)d_in[3]; // 512
    const float* w2      = (const float*)d_in[4]; // 512
    const float* b2      = (const float*)d_in[5]; // 1
    float* out = (float*)d_out;
    float* ws  = (float*)d_ws;

    // ws layout (floats): EA[512][256], EM[512][2048], partial[8][256][2048] => 21.5 MB
    float* EA      = ws;
    float* EM      = ws + 131072;
    float* partial = ws + 1179648;

    // Both GEMMs in one dispatch (z selects); exp(2x) epilogue
    gemm_exp<<<dim3(32, 8, 2), 256, 0, stream>>>(patient, atc4, W1, b1, EA, EM);
    // score partials: one rcp per 4 h-terms, packed-fp32 (float2) math
    pair_kernel<<<dim3(32, 8, 8), 256, 0, stream>>>(EA, EM, w2, partial);
    // sum 8 h-chunks + b2
    reduce_kernel<<<512, 256, 0, stream>>>(partial, b2, out);
}

// Round 9
// 120.307 us; speedup vs baseline: 1.2916x; 1.2916x over previous
//
#include <hip/hip_runtime.h>
#include <hip/hip_bf16.h>
#include <math.h>

// Problem constants: B=256, V=2048, PD=1024, MD=512, H=512
typedef __attribute__((ext_vector_type(8))) short short8;
typedef __attribute__((ext_vector_type(4))) short short4v;
typedef __attribute__((ext_vector_type(4))) float float4v;
typedef __attribute__((ext_vector_type(2))) float float2v;

// SSA-safe half extraction (NO unions -- r8's union blocked SROA and spilled
// the whole inner loop to scratch: VGPR 32, 187 MB scratch writes).
__device__ __forceinline__ float2v lo2(float4v v) {
    return __builtin_shufflevector(v, v, 0, 1);
}
__device__ __forceinline__ float2v hi2(float4v v) {
    return __builtin_shufflevector(v, v, 2, 3);
}

__device__ __forceinline__ int2 cvt2bf16x4(float4v v) {
    union { __hip_bfloat162 h2; int i; } u0, u1;
    u0.h2 = __float22bfloat162_rn(make_float2(v.x, v.y));  // v_cvt_pk_bf16_f32
    u1.h2 = __float22bfloat162_rn(make_float2(v.z, v.w));
    return make_int2(u0.i, u1.i);
}

// Fused dual GEMM + exp epilogue (plain [h][x] layout, contiguous stores).
//  z==0: EA[h][b] = exp(2*(patient@W1p^T + b1))   M=256,  K=1024
//  z==1: EM[h][v] = exp(2*(atc4@W1m^T))           M=2048, K=512
__global__ __launch_bounds__(256) void gemm_exp(
    const float* __restrict__ patient, const float* __restrict__ atc4,
    const float* __restrict__ W1, const float* __restrict__ b1,
    float* __restrict__ EA, float* __restrict__ EM)
{
    const float* A; const float* W; const float* bias; float* T;
    int lda, K, M;
    if (blockIdx.z == 0) {
        if (blockIdx.x >= 4) return;           // 4x8 tiles cover 256x512
        A = patient; lda = 1024; K = 1024; M = 256; bias = b1; T = EA; W = W1;
    } else {
        A = atc4;    lda = 512;  K = 512;  M = 2048; bias = nullptr; T = EM; W = W1 + 1024;
    }
    const int ldw = 1536;

    __shared__ short As[64][72];
    __shared__ short Bs[64][72];
    const int t = threadIdx.x;
    const int m0 = blockIdx.x * 64;
    const int n0 = blockIdx.y * 64;
    const int wave = t >> 6;
    const int lane = t & 63;
    const int wm = (wave & 1) * 32;
    const int wn = (wave >> 1) * 32;
    const int lrow = lane & 15;
    const int quad = lane >> 4;

    float4v acc[2][2];
    #pragma unroll
    for (int i = 0; i < 2; i++)
        #pragma unroll
        for (int j = 0; j < 2; j++)
            acc[i][j] = (float4v){0.f, 0.f, 0.f, 0.f};

    const int sr = t >> 2;        // staging row 0..63
    const int sc = (t & 3) * 16;  // staging col 0,16,32,48

    for (int k0 = 0; k0 < K; k0 += 64) {
        const float* ap = A + (size_t)(m0 + sr) * lda + (k0 + sc);
        const float* wp = W + (size_t)(n0 + sr) * ldw + (k0 + sc);
        #pragma unroll
        for (int ii = 0; ii < 4; ii++) {
            float4v av = *(const float4v*)(ap + ii * 4);
            float4v wv = *(const float4v*)(wp + ii * 4);
            *(int2*)&As[sr][sc + ii * 4] = cvt2bf16x4(av);
            *(int2*)&Bs[sr][sc + ii * 4] = cvt2bf16x4(wv);
        }
        __syncthreads();
        #pragma unroll
        for (int kk = 0; kk < 64; kk += 32) {
            short8 af[2], bfr[2];
            #pragma unroll
            for (int i = 0; i < 2; i++)
                af[i] = *(const short8*)&As[wm + i * 16 + lrow][kk + quad * 8];
            #pragma unroll
            for (int j = 0; j < 2; j++)
                bfr[j] = *(const short8*)&Bs[wn + j * 16 + lrow][kk + quad * 8];
            #pragma unroll
            for (int i = 0; i < 2; i++)
                #pragma unroll
                for (int j = 0; j < 2; j++)
                    acc[i][j] = __builtin_amdgcn_mfma_f32_16x16x32_bf16(
                        af[i], bfr[j], acc[i][j], 0, 0, 0);
        }
        __syncthreads();
    }

    // D layout (verified m89/m91): col(n)=lane&15, row(m)=quad*4+reg
    #pragma unroll
    for (int i = 0; i < 2; i++) {
        #pragma unroll
        for (int j = 0; j < 2; j++) {
            const int n  = n0 + wn + j * 16 + lrow;
            const int mb = m0 + wm + i * 16 + quad * 4;
            const float bn = bias ? bias[n] : 0.0f;
            float4v ev;
            #pragma unroll
            for (int r = 0; r < 4; r++)
                ev[r] = __expf(2.0f * (acc[i][j][r] + bn));
            *(float4v*)&T[(size_t)n * M + mb] = ev;
        }
    }
}

// partial[z][b][v] = sum_{h in 64-chunk z} [ w2[h] + c_h / d_h ],
//   c = -2*w2, d = 1 + Ea[h][b]*Em[h][v]    (w2*tanh(x) = w2 - 2*w2/(1+e^{2x}))
// 4-way h-pairing: one rcp per 4 h-terms,
//   sum_k c_k/d_k = (n01*e23 + n23*e01)/(e01*e23),  n01=c0*d1+c1*d0, e01=d0*d1.
//   All d >= 1: products bounded, no cancellation.
// Inner math on float2 SSA values (shufflevector halves of the float4 LDS
// loads) -> v_pk_fma_f32 / v_pk_mul_f32 packed fp32.
// Tile: 64 v x 32 b x 64 h. Grid (32, 8, 8) = 2048 blocks (8/CU residency).
__global__ __launch_bounds__(256, 8) void pair_kernel(
    const float* __restrict__ EA, const float* __restrict__ EM,
    const float* __restrict__ w2, float* __restrict__ partial)
{
    __shared__ float sEA[32][36];   // [h][b], 32 cols used
    __shared__ float sEM[32][68];   // [h][v], 64 cols used
    __shared__ float4v sC4[16];     // -2*w2 quads for the 64-h chunk
    const int t  = threadIdx.x;
    const int v0 = blockIdx.x * 64;
    const int b0 = blockIdx.y * 32;
    const int h0 = blockIdx.z * 64;
    const int tx = t & 15;   // v = v0 + tx*4 + j
    const int ty = t >> 4;   // b = b0 + ty*2 + i

    if (t < 16) {
        float4v wv = *(const float4v*)(w2 + h0 + 4 * t);
        sC4[t] = -2.0f * wv;
    }

    float2v accL[2], accH[2];
    accL[0] = (float2v){0.f, 0.f};  accL[1] = (float2v){0.f, 0.f};
    accH[0] = (float2v){0.f, 0.f};  accH[1] = (float2v){0.f, 0.f};
    const float2v one2 = {1.f, 1.f};

    const int rS = t >> 3;          // staging row 0..31
    const int cA = (t & 7) * 4;     // EA cols (32/row, 1 float4)
    const int cM = (t & 7) * 8;     // EM cols (64/row, 2 float4)

    float4v pA, pM0, pM1;
    // ---- load half 0 (h0 .. h0+31) ----
    {
        pA  = *(const float4v*)(EA + (size_t)(h0 + rS) * 256 + b0 + cA);
        const float* pm = EM + (size_t)(h0 + rS) * 2048 + v0 + cM;
        pM0 = *(const float4v*)pm;  pM1 = *(const float4v*)(pm + 4);
    }
    *(float4v*)&sEA[rS][cA] = pA;
    *(float4v*)&sEM[rS][cM] = pM0;  *(float4v*)&sEM[rS][cM + 4] = pM1;
    __syncthreads();
    // ---- prefetch half 1 into registers (in flight during compute 0) ----
    {
        pA  = *(const float4v*)(EA + (size_t)(h0 + 32 + rS) * 256 + b0 + cA);
        const float* pm = EM + (size_t)(h0 + 32 + rS) * 2048 + v0 + cM;
        pM0 = *(const float4v*)pm;  pM1 = *(const float4v*)(pm + 4);
    }

    #pragma unroll
    for (int half = 0; half < 2; half++) {
        #pragma unroll 2
        for (int q = 0; q < 8; q++) {           // 4 h per iteration
            const int hq = 4 * q;
            const float4v em0 = *(const float4v*)&sEM[hq    ][tx * 4];
            const float4v em1 = *(const float4v*)&sEM[hq + 1][tx * 4];
            const float4v em2 = *(const float4v*)&sEM[hq + 2][tx * 4];
            const float4v em3 = *(const float4v*)&sEM[hq + 3][tx * 4];
            const float2v em0L = lo2(em0), em0H = hi2(em0);
            const float2v em1L = lo2(em1), em1H = hi2(em1);
            const float2v em2L = lo2(em2), em2H = hi2(em2);
            const float2v em3L = lo2(em3), em3H = hi2(em3);
            // both b's ea per h-row as one float2 (broadcast, conflict-free)
            const float2v ea0 = *(const float2v*)&sEA[hq    ][ty * 2];
            const float2v ea1 = *(const float2v*)&sEA[hq + 1][ty * 2];
            const float2v ea2 = *(const float2v*)&sEA[hq + 2][ty * 2];
            const float2v ea3 = *(const float2v*)&sEA[hq + 3][ty * 2];
            const float4v c = sC4[half * 8 + q];
            const float2v c0 = { c.x, c.x };
            const float2v c1 = { c.y, c.y };
            const float2v c2 = { c.z, c.z };
            const float2v c3 = { c.w, c.w };
            #pragma unroll
            for (int i = 0; i < 2; i++) {
                const float2v a0 = { ea0[i], ea0[i] };
                const float2v a1 = { ea1[i], ea1[i] };
                const float2v a2 = { ea2[i], ea2[i] };
                const float2v a3 = { ea3[i], ea3[i] };
                // ---- low float2 of the v-quad ----
                {
                    float2v d0 = __builtin_elementwise_fma(em0L, a0, one2);
                    float2v d1 = __builtin_elementwise_fma(em1L, a1, one2);
                    float2v d2 = __builtin_elementwise_fma(em2L, a2, one2);
                    float2v d3 = __builtin_elementwise_fma(em3L, a3, one2);
                    float2v e01 = d0 * d1;
                    float2v e23 = d2 * d3;
                    float2v n01 = __builtin_elementwise_fma(d1, c0, d0 * c1);
                    float2v n23 = __builtin_elementwise_fma(d3, c2, d2 * c3);
                    float2v num = __builtin_elementwise_fma(n01, e23, n23 * e01);
                    float2v den = e01 * e23;
                    float2v r = { __builtin_amdgcn_rcpf(den.x),
                                  __builtin_amdgcn_rcpf(den.y) };
                    accL[i] = __builtin_elementwise_fma(num, r, accL[i]);
                }
                // ---- high float2 of the v-quad ----
                {
                    float2v d0 = __builtin_elementwise_fma(em0H, a0, one2);
                    float2v d1 = __builtin_elementwise_fma(em1H, a1, one2);
                    float2v d2 = __builtin_elementwise_fma(em2H, a2, one2);
                    float2v d3 = __builtin_elementwise_fma(em3H, a3, one2);
                    float2v e01 = d0 * d1;
                    float2v e23 = d2 * d3;
                    float2v n01 = __builtin_elementwise_fma(d1, c0, d0 * c1);
                    float2v n23 = __builtin_elementwise_fma(d3, c2, d2 * c3);
                    float2v num = __builtin_elementwise_fma(n01, e23, n23 * e01);
                    float2v den = e01 * e23;
                    float2v r = { __builtin_amdgcn_rcpf(den.x),
                                  __builtin_amdgcn_rcpf(den.y) };
                    accH[i] = __builtin_elementwise_fma(num, r, accH[i]);
                }
            }
        }
        if (half == 0) {
            __syncthreads();   // compute(0) done reading LDS
            *(float4v*)&sEA[rS][cA] = pA;
            *(float4v*)&sEM[rS][cM] = pM0;  *(float4v*)&sEM[rS][cM + 4] = pM1;
            __syncthreads();
        }
    }

    // chunk's sum(w2) from sC4 (sC4 = -2*w2)
    float4v w2q = sC4[0];
    for (int k = 1; k < 16; k++) w2q += sC4[k];
    const float w2s = -0.5f * (w2q.x + w2q.y + w2q.z + w2q.w);

    const size_t pb = (size_t)blockIdx.z * (256 * 2048);
    #pragma unroll
    for (int i = 0; i < 2; i++) {
        float4v o = { accL[i].x + w2s, accL[i].y + w2s,
                      accH[i].x + w2s, accH[i].y + w2s };
        *(float4v*)&partial[pb + (size_t)(b0 + ty * 2 + i) * 2048 + v0 + tx * 4] = o;
    }
}

__global__ __launch_bounds__(256) void reduce_kernel(
    const float* __restrict__ partial, const float* __restrict__ b2,
    float* __restrict__ out)
{
    const int i = (blockIdx.x * 256 + threadIdx.x) * 4;
    const float bb = b2[0];
    float4v s = *(const float4v*)&partial[i];
    #pragma unroll
    for (int z = 1; z < 8; z++)
        s += *(const float4v*)&partial[(size_t)z * 524288 + i];
    float4v o = s + bb;
    *(float4v*)&out[i] = o;
}

extern "C" void kernel_launch(void* const* d_in, const int* in_sizes, int n_in,
                              void* d_out, int out_size, void* d_ws, size_t ws_size,
                              hipStream_t stream)
{
    const float* patient = (const float*)d_in[0]; // 256x1024
    const float* atc4    = (const float*)d_in[1]; // 2048x512
    const float* W1      = (const float*)d_in[2]; // 512x1536
    const float* b1      = (const float*)d_in[3]; // 512
    const float* w2      = (const float*)d_in[4]; // 512
    const float* b2      = (const float*)d_in[5]; // 1
    float* out = (float*)d_out;
    float* ws  = (float*)d_ws;

    // ws layout (floats): EA[512][256], EM[512][2048], partial[8][256][2048] => 21.5 MB
    float* EA      = ws;
    float* EM      = ws + 131072;
    float* partial = ws + 1179648;

    // Both GEMMs in one dispatch (z selects); exp(2x) epilogue
    gemm_exp<<<dim3(32, 8, 2), 256, 0, stream>>>(patient, atc4, W1, b1, EA, EM);
    // score partials: one rcp per 4 h-terms, packed-fp32 via SSA float2 halves
    pair_kernel<<<dim3(32, 8, 8), 256, 0, stream>>>(EA, EM, w2, partial);
    // sum 8 h-chunks + b2
    reduce_kernel<<<512, 256, 0, stream>>>(partial, b2, out);
}